// Round 10
// baseline (323.032 us; speedup 1.0000x reference)
//
#include <hip/hip_runtime.h>
#include <hip/hip_bf16.h>

#define Bt 16
#define Ct 16
#define Nt 64
#define KITERt 4

// ---------- fp32 weight block offsets (floats) ----------
// wq@0(512) bq@512(32) wk@544(512) bk@1056(32) wm@1088(2304) bm@3392(16)
// w1@3408(4096) b1@7504(64) w2@7568(4096) b2@11664(64) wo@11728(64) bo@11792(1)
// gb@11793(16) wg@11809(9216) bg@21025(32) wc@21057(4608) bc@25665(16)
#define WF_TOTAL 25681
// 32x32x16 B-frag tables (bf16): WgS2 9216 | WcS2 9216 | WmS2 4608
#define SWZ_TOTAL 23040
#define TSWZ_TOTAL 8192
#define SETUP_IDX (WF_TOTAL + TSWZ_TOTAL + SWZ_TOTAL)

typedef __attribute__((ext_vector_type(8))) short bf16x8;
typedef __attribute__((ext_vector_type(4))) float f32x4;
typedef __attribute__((ext_vector_type(16))) float f32x16;

__device__ inline short f2bs(float f) {
    __hip_bfloat16 h = __float2bfloat16(f);
    short s; __builtin_memcpy(&s, &h, 2); return s;
}
__device__ inline float bs2f(short s) {
    __hip_bfloat16 h; __builtin_memcpy(&h, &s, 2);
    return __bfloat162float(h);
}
__device__ inline float loadf(const void* p, int i, int isf32) {
    return isf32 ? ((const float*)p)[i]
                 : __bfloat162float(((const __hip_bfloat16*)p)[i]);
}
__device__ inline float sigm(float x) {
    return __builtin_amdgcn_rcpf(1.f + __expf(-x));
}
__device__ inline float tanh_fast(float x) {
    float e = __expf(2.f * x);              // inf-safe: rcp(inf)=0 -> 1; e=0 -> -1
    return 1.f - 2.f * __builtin_amdgcn_rcpf(e + 1.f);
}

// ---------------- setup (256 thr x 1024 blocks): flag, weights->fp32, Tswz2,
// nbr table (parallel, direction-slot, ref edge order), 32x32 B-swizzles,
// unpack seed -> Xb bf16 [b][n][pix][ch], initial q/k ----------------
__global__ __launch_bounds__(256) void setup_kernel(
    const void* __restrict__ seed,
    const void* __restrict__ wq, const void* __restrict__ bq,
    const void* __restrict__ wk, const void* __restrict__ bk,
    const void* __restrict__ wm, const void* __restrict__ bm,
    const void* __restrict__ w1, const void* __restrict__ b1,
    const void* __restrict__ w2, const void* __restrict__ b2,
    const void* __restrict__ wo, const void* __restrict__ bo,
    const void* __restrict__ gw, const void* __restrict__ gb,
    const void* __restrict__ wg, const void* __restrict__ bg,
    const void* __restrict__ wc, const void* __restrict__ bc,
    const int* __restrict__ edge, int E,
    float* __restrict__ Wf, float* __restrict__ Tswz,
    int* __restrict__ counts, int* __restrict__ nbrs,
    __hip_bfloat16* __restrict__ swz,
    short* __restrict__ Xb, float* __restrict__ qv0, float* __restrict__ kv0,
    int* __restrict__ flag)
{
    __shared__ float sred[4];
    __shared__ int sflag;
    __shared__ float xred[64];
    __shared__ int snb[256];
    int bn = blockIdx.x, t = threadIdx.x;
    int lane = t & 63, wv = t >> 6;

    // ---- dtype probe: 1 sample/thread, block-reduce max of |bf16-view| ----
    {
        float v = fabsf(__bfloat162float(((const __hip_bfloat16*)seed)[t]));
        if (!(v <= 1e30f)) v = 1e30f;
#pragma unroll
        for (int off = 1; off < 64; off <<= 1) v = fmaxf(v, __shfl_xor(v, off, 64));
        if (lane == 0) sred[wv] = v;
        __syncthreads();
        if (t == 0) {
            float m = fmaxf(fmaxf(sred[0], sred[1]), fmaxf(sred[2], sred[3]));
            sflag = (m > 1e10f) ? 1 : 0;   // 1 => inputs are float32
            if (bn == 0) *flag = sflag;
        }
        __syncthreads();
    }
    int isf32 = sflag;

    // ---- block 0: parallel nbr table via direction slots (matches ref order) ----
    if (bn == 0) {
        if (t < 256) snb[t] = 0;
        __syncthreads();
        for (int e = t; e < E; e += 256) {
            int ei = edge[2 * e], ej = edge[2 * e + 1];
            int d = ej - ei;
            int slot = (d == 1) ? 0 : (d == 8) ? 1 : (d == -1) ? 2 : 3;
            snb[ei * 4 + slot] = ej + 1;   // 0 = absent
        }
        __syncthreads();
        if (t < 64) {
            int dcount = 0;
            int outv[4] = {0, 0, 0, 0};
#pragma unroll
            for (int s = 0; s < 4; ++s) {
                int v = snb[t * 4 + s];
                if (v) outv[dcount++] = v - 1;
            }
            counts[t] = dcount;
#pragma unroll
            for (int s = 0; s < 4; ++s) nbrs[t * 4 + s] = outv[s];
        }
    }

    // ---- part 1: indexed weight / table prep ----
    int idx = bn * 256 + t;
    if (idx < WF_TOTAL) {
        int i = idx;
        const void* base;
        if (i < 512) base = wq;
        else if ((i -= 512) < 32) base = bq;
        else if ((i -= 32) < 512) base = wk;
        else if ((i -= 512) < 32) base = bk;
        else if ((i -= 32) < 2304) base = wm;
        else if ((i -= 2304) < 16) base = bm;
        else if ((i -= 16) < 4096) base = w1;
        else if ((i -= 4096) < 64) base = b1;
        else if ((i -= 64) < 4096) base = w2;
        else if ((i -= 4096) < 64) base = b2;
        else if ((i -= 64) < 64) base = wo;
        else if ((i -= 64) < 1) base = bo;
        else if ((i -= 1) < 16) base = gb;
        else if ((i -= 16) < 9216) base = wg;
        else if ((i -= 9216) < 32) base = bg;
        else if ((i -= 32) < 4608) base = wc;
        else { i -= 4608; base = bc; }
        Wf[idx] = loadf(base, i, isf32);
    } else if (idx < WF_TOTAL + TSWZ_TOTAL) {
        // Tswz2[t2*16+r] = T[ch=n][pixel(wv2, half, r)] for n<16 else 0
        int j = idx - WF_TOTAL;
        int t2 = j >> 4, r = j & 15;
        int wv2 = t2 >> 6, ln = t2 & 63, n2 = ln & 31, hf2 = ln >> 5;
        float s = 0.f;
        if (n2 < 16) {
            int row = (r & 3) + 8 * (r >> 2) + 4 * hf2;
            int pix = wv2 * 32 + row;
            int y = pix >> 4, x = pix & 15;
            for (int ky = 0; ky < 3; ++ky)
                for (int kx = 0; kx < 3; ++kx) {
                    int yy = y + ky - 1, xx = x + kx - 1;
                    if (yy >= 0 && yy < 16 && xx >= 0 && xx < 16)
                        s += loadf(gw, n2 * 9 + ky * 3 + kx, isf32);
                }
        }
        Tswz[j] = s;
    } else if (idx < SETUP_IDX) {
        // 32x32x16 B swizzles: element j8 of lane ln = B[k=(ln>>5)*8+j8][nn=ln&31]
        int j = idx - (WF_TOTAL + TSWZ_TOTAL);
        float val;
        if (j < 9216) {                       // WgS2: [s][c][ln][j8]
            int s = j >> 10, rem = j & 1023;
            int c = rem >> 9, ln = (rem >> 3) & 63, j8 = rem & 7;
            int nn = ln & 31, hf2 = ln >> 5;
            int ci = c * 16 + hf2 * 8 + j8;
            val = loadf(wg, nn * 288 + ci * 9 + s, isf32);
        } else if (j < 18432) {               // WcS2: [s][c][ln][j8], n>=16 -> 0
            int j1 = j - 9216;
            int s = j1 >> 10, rem = j1 & 1023;
            int c = rem >> 9, ln = (rem >> 3) & 63, j8 = rem & 7;
            int nn = ln & 31, hf2 = ln >> 5;
            int ci = c * 16 + hf2 * 8 + j8;
            val = (nn < 16) ? loadf(wc, nn * 288 + ci * 9 + s, isf32) : 0.f;
        } else {                              // WmS2: [s][ln][j8], n>=16 -> 0
            int j2 = j - 18432;
            int s = j2 >> 9, ln = (j2 >> 3) & 63, j8 = j2 & 7;
            int nn = ln & 31, hf2 = ln >> 5;
            int ci = hf2 * 8 + j8;
            val = (nn < 16) ? loadf(wm, nn * 144 + ci * 9 + s, isf32) : 0.f;
        }
        swz[j] = __float2bfloat16(val);
    }

    // ---- part 2: unpack own patch bn + initial q/k (raw inputs only) ----
    {
        int b = bn >> 6, n = bn & 63;
        int pq = n >> 3, qq = n & 7;
        int y = t >> 4, x = t & 15;
        float v[16];
#pragma unroll
        for (int c = 0; c < 16; ++c)
            v[c] = loadf(seed, ((b * 16 + c) * 128 + pq * 16 + y) * 128 + qq * 16 + x, isf32);
        bf16x8 o0, o1;
#pragma unroll
        for (int c = 0; c < 8; ++c) { o0[c] = f2bs(v[c]); o1[c] = f2bs(v[8 + c]); }
        short* xo = Xb + bn * 4096;
        *(bf16x8*)(xo + t * 16) = o0;
        *(bf16x8*)(xo + t * 16 + 8) = o1;
#pragma unroll
        for (int c = 0; c < 16; ++c) {
            float s = v[c];
#pragma unroll
            for (int off = 1; off < 64; off <<= 1) s += __shfl_xor(s, off, 64);
            if (lane == c) xred[wv * 16 + c] = s;
        }
        __syncthreads();
        if (t < 64) {
            int d = t & 31;
            float a = (t < 32) ? loadf(bq, d, isf32) : loadf(bk, d, isf32);
#pragma unroll
            for (int c = 0; c < 16; ++c) {
                float xm = (xred[c] + xred[16 + c] + xred[32 + c] + xred[48 + c]) * (1.f / 256.f);
                a += xm * ((t < 32) ? loadf(wq, c * 32 + d, isf32)
                                    : loadf(wk, c * 32 + d, isf32));
            }
            if (t < 32) qv0[bn * 32 + d] = a; else kv0[bn * 32 + d] = a;
        }
    }
}

// ---------------- fused iteration: 512 threads (8 waves), one block per (b,patch) ----
// 32x32x16 MFMA; wave wv owns M-tile = pixels [wv*32, wv*32+32).
// Lane roles: n=lane&31 (A row / output col), half=lane>>5 (K-block).
__global__ __launch_bounds__(512) void iter_kernel(
    const short* __restrict__ Xin, short* __restrict__ Xout,
    const float* __restrict__ qin, const float* __restrict__ kin,
    float* __restrict__ qout, float* __restrict__ kout,
    const float* __restrict__ Tswz,
    const short* __restrict__ WmS,
    const short* __restrict__ WgS,
    const short* __restrict__ WcS,
    const float* __restrict__ Wf,
    const int* __restrict__ counts, const int* __restrict__ nbrs,
    const int* __restrict__ flagp, void* __restrict__ out, int last)
{
    __shared__ __align__(16) short sAH[324 * 40];  // [pad-pix][ch0-15=nbr/Magg, ch16-31=h/rh, 8 pad]
    __shared__ float evs[4];
    __shared__ float xred[128];
    int bn = blockIdx.x, b = bn >> 6, i = bn & 63;
    int t = threadIdx.x, lane = t & 63, wv = t >> 6;   // wv 0..7
    int n = lane & 31, half = lane >> 5;

    // ---- nbr table (one int4) + neighbor-0 prefetch (half pixel per thread) ----
    int4 nb4 = *(const int4*)(nbrs + i * 4);
    int deg = counts[i];
    int ejl[4] = {nb4.x, nb4.y, nb4.z, nb4.w};
    int hp = t >> 1, ho = (t & 1) * 8;      // pixel 0..255, 8-ch offset
    bf16x8 nbA, nbB;
    if (deg > 0)
        nbA = *(const bf16x8*)(Xin + (b * 64 + ejl[0]) * 4096 + hp * 16 + ho);

    // per-lane T (16 floats, C-layout order) + gate bias
    float T_lane[16];
    {
        const f32x4* tp = (const f32x4*)(Tswz + t * 16);
        f32x4 t0 = tp[0], t1 = tp[1], t2 = tp[2], t3 = tp[3];
#pragma unroll
        for (int r = 0; r < 4; ++r) {
            T_lane[r] = t0[r]; T_lane[4 + r] = t1[r];
            T_lane[8 + r] = t2[r]; T_lane[12 + r] = t3[r];
        }
    }
    float gb_l = Wf[11793 + (n & 15)];

    const short* xown = Xin + bn * 4096;

    // ---- phase A: own h -> ch16-31; zero borders (all 32 ch); stage nb0 ----
    if (t < 324) {
        int yy = t / 18 - 1, xx = t % 18 - 1;
        short* row = sAH + t * 40;
        if ((unsigned)yy < 16u && (unsigned)xx < 16u) {
            const short* src = xown + (yy * 16 + xx) * 16;
            *(bf16x8*)(row + 16) = *(const bf16x8*)(src);
            *(bf16x8*)(row + 24) = *(const bf16x8*)(src + 8);
        } else {
            bf16x8 z = {0, 0, 0, 0, 0, 0, 0, 0};
            *(bf16x8*)(row) = z;      *(bf16x8*)(row + 8) = z;
            *(bf16x8*)(row + 16) = z; *(bf16x8*)(row + 24) = z;
        }
    }
    int sstage = (((hp >> 4) + 1) * 18 + (hp & 15) + 1) * 40 + ho;
    if (deg > 0) *(bf16x8*)(sAH + sstage) = nbA;

    // ---- phase B: edge MLP, wave wv handles edge wv ----
    if (wv < deg) {
        int ej = ejl[wv];
        float h0 = (lane < 32) ? qin[bn * 32 + lane]
                               : kin[(b * 64 + ej) * 32 + (lane - 32)];
        const float* W1 = Wf + 3408;
        const float* W2 = Wf + 7568;
        float p0 = 0.f, p1 = 0.f, p2 = 0.f, p3 = 0.f;
#pragma unroll
        for (int j = 0; j < 64; j += 4) {
            p0 += __shfl(h0, j + 0, 64) * W1[(j + 0) * 64 + lane];
            p1 += __shfl(h0, j + 1, 64) * W1[(j + 1) * 64 + lane];
            p2 += __shfl(h0, j + 2, 64) * W1[(j + 2) * 64 + lane];
            p3 += __shfl(h0, j + 3, 64) * W1[(j + 3) * 64 + lane];
        }
        float a1 = fmaxf(Wf[7504 + lane] + ((p0 + p1) + (p2 + p3)), 0.f);
        p0 = p1 = p2 = p3 = 0.f;
#pragma unroll
        for (int j = 0; j < 64; j += 4) {
            p0 += __shfl(a1, j + 0, 64) * W2[(j + 0) * 64 + lane];
            p1 += __shfl(a1, j + 1, 64) * W2[(j + 1) * 64 + lane];
            p2 += __shfl(a1, j + 2, 64) * W2[(j + 2) * 64 + lane];
            p3 += __shfl(a1, j + 3, 64) * W2[(j + 3) * 64 + lane];
        }
        float a2 = fmaxf(Wf[11664 + lane] + ((p0 + p1) + (p2 + p3)), 0.f);
        float pe = a2 * Wf[11728 + lane];
#pragma unroll
        for (int off = 32; off; off >>= 1) pe += __shfl_down(pe, off, 64);
        if (lane == 0) evs[wv] = pe + Wf[11792];
    }
    __syncthreads();   // h + nb0 staged, evs ready

    // A-frag base (shorts): lane's pixel m=n -> (y,x); +half*8 selects K-block
    const short* Ab = sAH + ((2 * wv + (n >> 4)) * 18 + (n & 15)) * 40 + half * 8;

    // ---- phase C: per-neighbor M conv (9 MFMA) + gated accumulate ----
    float magg[16];
#pragma unroll
    for (int r = 0; r < 16; ++r) magg[r] = 0.f;
    float bm_l = (n < 16) ? Wf[3392 + n] : 0.f;
    for (int ii = 0; ii < deg; ++ii) {
        if (ii + 1 < deg)
            nbB = *(const bf16x8*)(Xin + (b * 64 + ejl[ii + 1]) * 4096 + hp * 16 + ho);
        float evv = evs[ii];
        f32x16 acc;
#pragma unroll
        for (int r = 0; r < 16; ++r) acc[r] = bm_l;
#pragma unroll
        for (int s = 0; s < 9; ++s) {
            int ky = s / 3, kx = s - (s / 3) * 3;
            bf16x8 Bf = *(const bf16x8*)(WmS + (s * 64 + lane) * 8);
            bf16x8 A = *(const bf16x8*)(Ab + (ky * 18 + kx) * 40);
            acc = __builtin_amdgcn_mfma_f32_32x32x16_bf16(A, Bf, acc, 0, 0, 0);
        }
#pragma unroll
        for (int r = 0; r < 16; ++r)
            magg[r] += sigm(evv * T_lane[r] + gb_l) * acc[r];
        __syncthreads();                       // conv reads of this tile done
        if (ii + 1 < deg) *(bf16x8*)(sAH + sstage) = nbB;
        __syncthreads();                       // next tile staged
    }
    // ---- phase D: M_agg -> ch0-15 interior (C-layout scalars, lanes n<16) ----
    if (n < 16) {
#pragma unroll
        for (int r = 0; r < 16; ++r) {
            int row = (r & 3) + 8 * (r >> 2) + 4 * half;
            int py = 2 * wv + (row >> 4), px = row & 15;
            sAH[((py + 1) * 18 + px + 1) * 40 + n] = f2bs(magg[r]);
        }
    }
    __syncthreads();

    // ---- zr conv: 9 shifts x 2 K-chunks, N=32 covers z(0-15)+r(16-31) ----
    f32x16 azr;
    {
        float bg_l = Wf[21025 + n];
#pragma unroll
        for (int r = 0; r < 16; ++r) azr[r] = bg_l;
    }
#pragma unroll
    for (int s = 0; s < 9; ++s) {
        int ky = s / 3, kx = s - (s / 3) * 3;
#pragma unroll
        for (int c = 0; c < 2; ++c) {
            bf16x8 Bf = *(const bf16x8*)(WgS + ((s * 2 + c) * 64 + lane) * 8);
            bf16x8 A = *(const bf16x8*)(Ab + (ky * 18 + kx) * 40 + c * 16);
            azr = __builtin_amdgcn_mfma_f32_32x32x16_bf16(A, Bf, azr, 0, 0, 0);
        }
    }
    // ---- h read (all lanes: ch = n&15); z (n<16) / rh->LDS (n>=16) ----
    float hf[16], zf[16];
#pragma unroll
    for (int r = 0; r < 16; ++r) {
        int row = (r & 3) + 8 * (r >> 2) + 4 * half;
        int py = 2 * wv + (row >> 4), px = row & 15;
        hf[r] = bs2f(sAH[((py + 1) * 18 + px + 1) * 40 + 16 + (n & 15)]);
    }
    __syncthreads();   // all h reads done before rh overwrite
    if (n >= 16) {
#pragma unroll
        for (int r = 0; r < 16; ++r) {
            int row = (r & 3) + 8 * (r >> 2) + 4 * half;
            int py = 2 * wv + (row >> 4), px = row & 15;
            sAH[((py + 1) * 18 + px + 1) * 40 + 16 + (n & 15)] =
                f2bs(sigm(azr[r]) * hf[r]);
        }
    } else {
#pragma unroll
        for (int r = 0; r < 16; ++r) zf[r] = sigm(azr[r]);
    }
    __syncthreads();

    // ---- cand conv: 9 shifts x 2 K-chunks (N 16-31 wasted) ----
    f32x16 acd;
    {
        float bc_l = (n < 16) ? Wf[25665 + n] : 0.f;
#pragma unroll
        for (int r = 0; r < 16; ++r) acd[r] = bc_l;
    }
#pragma unroll
    for (int s = 0; s < 9; ++s) {
        int ky = s / 3, kx = s - (s / 3) * 3;
#pragma unroll
        for (int c = 0; c < 2; ++c) {
            bf16x8 Bf = *(const bf16x8*)(WcS + ((s * 2 + c) * 64 + lane) * 8);
            bf16x8 A = *(const bf16x8*)(Ab + (ky * 18 + kx) * 40 + c * 16);
            acd = __builtin_amdgcn_mfma_f32_32x32x16_bf16(A, Bf, acd, 0, 0, 0);
        }
    }
    // ---- epilogue (lanes n<16): nx = (1-z)h + z*tanh(cand); store; q/k sums ----
    if (n < 16) {
        float ssum = 0.f;
        int isf32 = *flagp;
        int pq = i >> 3, qq = i & 7;
#pragma unroll
        for (int r = 0; r < 16; ++r) {
            int row = (r & 3) + 8 * (r >> 2) + 4 * half;
            int py = 2 * wv + (row >> 4), px = row & 15;
            float nx = (1.f - zf[r]) * hf[r] + zf[r] * tanh_fast(acd[r]);
            ssum += nx;
            if (!last) {
                Xout[bn * 4096 + (py * 16 + px) * 16 + n] = f2bs(nx);
            } else {
                long base = ((long)(b * 16 + n) * 128 + pq * 16 + py) * 128 + qq * 16 + px;
                if (isf32) ((float*)out)[base] = nx;
                else ((short*)out)[base] = f2bs(nx);
            }
        }
        ssum += __shfl_xor(ssum, 32, 64);   // lanes 0-15 <-> 32-47, both active
        if (lane < 16) xred[wv * 16 + n] = ssum;
    }
    if (!last) {
        __syncthreads();
        if (t < 64) {
            int d = t & 31;
            const float* W = (t < 32) ? Wf : Wf + 544;
            float a = (t < 32) ? Wf[512 + d] : Wf[1056 + d];
#pragma unroll
            for (int c = 0; c < 16; ++c) {
                float xc = 0.f;
#pragma unroll
                for (int w = 0; w < 8; ++w) xc += xred[w * 16 + c];
                a += xc * (1.f / 256.f) * W[c * 32 + d];
            }
            if (t < 32) qout[bn * 32 + d] = a; else kout[bn * 32 + d] = a;
        }
    }
}

extern "C" void kernel_launch(void* const* d_in, const int* in_sizes, int n_in,
                              void* d_out, int out_size, void* d_ws, size_t ws_size,
                              hipStream_t stream)
{
    const void* seed = d_in[0];
    const int* edge = (const int*)d_in[1];
    int E = in_sizes[1] / 2;  // 224

    float* ws = (float*)d_ws;
    short* Xb0 = (short*)ws;                         // 8 MB
    short* Xb1 = (short*)(ws + 2097152);             // 8 MB
    float* qv0 = ws + 4194304;                       // 32768 each
    float* kv0 = qv0 + 32768;
    float* qv1 = kv0 + 32768;
    float* kv1 = qv1 + 32768;
    float* Tswz = ws + 4325376;                      // 8192
    float* Wf = ws + 4333568;                        // 25681
    int* nbrs = (int*)(ws + 4360000);                // 256, 16B-aligned
    int* counts = nbrs + 256;                        // 64
    int* flag = counts + 64;                         // 1
    __hip_bfloat16* swz = (__hip_bfloat16*)(ws + 4360400);  // 23040 bf16, 16B-aligned

    const short* WgS = (const short*)swz;            // 9216
    const short* WcS = (const short*)(swz + 9216);   // 9216
    const short* WmS = (const short*)(swz + 18432);  // 4608

    setup_kernel<<<Bt * Nt, 256, 0, stream>>>(
        seed,
        d_in[2], d_in[3], d_in[4], d_in[5], d_in[6], d_in[7], d_in[8], d_in[9],
        d_in[10], d_in[11], d_in[12], d_in[13], d_in[14], d_in[15], d_in[16],
        d_in[17], d_in[18], d_in[19],
        edge, E, Wf, Tswz, counts, nbrs, swz, Xb0, qv0, kv0, flag);

    short* Xs[2] = {Xb0, Xb1};
    float* qs[2] = {qv0, qv1};
    float* ks[2] = {kv0, kv1};
    for (int it = 0; it < KITERt; ++it) {
        int in = it & 1, on = in ^ 1;
        int last = (it == KITERt - 1);
        iter_kernel<<<Bt * Nt, 512, 0, stream>>>(
            Xs[in], Xs[on], qs[in], ks[in], qs[on], ks[on],
            Tswz, WmS, WgS, WcS, Wf, counts, nbrs, flag, d_out, last);
    }
}